// Round 7
// baseline (464.060 us; speedup 1.0000x reference)
//
#include <hip/hip_runtime.h>
#include <cmath>

typedef unsigned short u16;
typedef __attribute__((ext_vector_type(8))) short bf16x8;
typedef __attribute__((ext_vector_type(4))) float f32x4;
typedef __attribute__((ext_vector_type(16))) float f32x16;

#define MFMA(a,b,c)   __builtin_amdgcn_mfma_f32_16x16x32_bf16((a),(b),(c),0,0,0)
#define MFMA32(a,b,c) __builtin_amdgcn_mfma_f32_32x32x16_bf16((a),(b),(c),0,0,0)

__device__ __forceinline__ float bf2f(u16 u){ return __uint_as_float(((unsigned)u)<<16); }
__device__ __forceinline__ u16 f2bf(float f){
  unsigned x = __float_as_uint(f);
  return (u16)((x + 0x7FFFu + ((x>>16)&1u)) >> 16);
}

__device__ __forceinline__ void gll16(const u16* g, u16* l){
  __builtin_amdgcn_global_load_lds((const __attribute__((address_space(1))) unsigned*)g,
                                   (__attribute__((address_space(3))) unsigned*)l, 16, 0, 0);
}

// ---------- prep: transpose + re-layout to slab-contiguous bf16 ----------
// w1 (E,D,H) -> w1t2[e][kd=d>>4][h][d&15]  (slab (e,kd) = 512 rows x 32B = 16KB)
// w2 (E,H,D) -> w2t2[e][kh=h>>4][d][h&15]  (slab (e,kh) = 256 rows x 32B = 8KB)
__global__ __launch_bounds__(256) void k_transpose(const float* __restrict__ w1,
        const float* __restrict__ w2, u16* __restrict__ w1t2, u16* __restrict__ w2t2){
  __shared__ u16 t[64][66];
  int b = blockIdx.x;
  int c0 = threadIdx.x & 63, r0 = threadIdx.x >> 6;
  if (b < 192){            // w1: src (D=256 x H=512)
    int e = b >> 5, tl = b & 31;
    int tr = (tl >> 3) << 6, tc = (tl & 7) << 6;
    const float* src = w1 + (size_t)e*131072;
    u16* dst = w1t2 + (size_t)e*131072;
    #pragma unroll
    for (int i=0;i<16;++i){
      int r = r0 + i*4;
      t[c0][r] = f2bf(src[(size_t)(tr+r)*512 + tc + c0]);   // coalesced along H
    }
    __syncthreads();
    #pragma unroll
    for (int i=0;i<16;++i){
      int cc = r0 + i*4;
      int h = tc + cc, d = tr + c0;
      dst[(size_t)((d>>4)*512 + h)*16 + (d&15)] = t[cc][c0];
    }
  } else {                 // w2: src (H=512 x D=256)
    int bb = b - 192;
    int e = bb >> 5, tl = bb & 31;
    int tr = (tl >> 2) << 6, tc = (tl & 3) << 6;
    const float* src = w2 + (size_t)e*131072;
    u16* dst = w2t2 + (size_t)e*131072;
    #pragma unroll
    for (int i=0;i<16;++i){
      int r = r0 + i*4;
      t[c0][r] = f2bf(src[(size_t)(tr+r)*256 + tc + c0]);   // coalesced along D
    }
    __syncthreads();
    #pragma unroll
    for (int i=0;i<16;++i){
      int cc = r0 + i*4;
      int d = tc + cc, h = tr + c0;
      dst[(size_t)((h>>4)*256 + d)*16 + (h&15)] = t[cc][c0];
    }
  }
}

// rw1 (261,256): first 256 rows -> [j][d] hi/lo bf16; rows 256..260 + rb1 folded into regb[b][j].
__global__ void k_prep_rw1(const float* __restrict__ rw1, const float* __restrict__ rb1,
                           const float* __restrict__ regime,
                           u16* __restrict__ rwh, u16* __restrict__ rwl,
                           float* __restrict__ regb){
  int idx = blockIdx.x*256 + threadIdx.x;  // 65536 + 2048 total
  if (idx < 65536){
    int dd = idx & 255, j = idx >> 8;
    float w = rw1[dd*256 + j];
    u16 hi = f2bf(w);
    rwh[idx] = hi;
    rwl[idx] = f2bf(w - bf2f(hi));
  } else {
    int i = idx - 65536; int j = i & 255, b = i >> 8;
    float v = rb1[j];
    #pragma unroll
    for (int r=0;r<5;++r) v += regime[b*5+r]*rw1[(256+r)*256 + j];
    regb[b*256 + j] = v;
  }
}

// ---------- LayerNorm: x -> xn hi/lo bf16 (wave per token) ----------
__global__ __launch_bounds__(256) void k_ln(const float* __restrict__ x,
        const float* __restrict__ g, const float* __restrict__ bta,
        u16* __restrict__ xh, u16* __restrict__ xl){
  int wv = threadIdx.x >> 6, lane = threadIdx.x & 63;
  int t = blockIdx.x*4 + wv;
  float4 v = ((const float4*)(x + (size_t)t*256))[lane];
  float s  = v.x+v.y+v.z+v.w;
  float ss = v.x*v.x+v.y*v.y+v.z*v.z+v.w*v.w;
  #pragma unroll
  for (int m=32;m>=1;m>>=1){ s += __shfl_xor(s,m); ss += __shfl_xor(ss,m); }
  float mu  = s*(1.f/256.f);
  float var = ss*(1.f/256.f) - mu*mu;
  float inv = 1.f / sqrtf(var + 1e-5f);
  float4 gv = ((const float4*)g)[lane];
  float4 bv = ((const float4*)bta)[lane];
  float xv[4] = {v.x,v.y,v.z,v.w};
  float gg[4] = {gv.x,gv.y,gv.z,gv.w};
  float bb[4] = {bv.x,bv.y,bv.z,bv.w};
  u16 hh[4], ll[4];
  #pragma unroll
  for (int q=0;q<4;++q){
    float xn = (xv[q]-mu)*inv*gg[q] + bb[q];
    u16 h = f2bf(xn);
    hh[q] = h;
    ll[q] = f2bf(xn - bf2f(h));
  }
  ((ushort4*)(xh + (size_t)t*256))[lane] = make_ushort4(hh[0],hh[1],hh[2],hh[3]);
  ((ushort4*)(xl + (size_t)t*256))[lane] = make_ushort4(ll[0],ll[1],ll[2],ll[3]);
}

// ---------- router GEMM (hi/lo MFMA, weight frags direct from L2) ----------
__global__ __launch_bounds__(256,2) void k_router(const u16* __restrict__ xh, const u16* __restrict__ xl,
        const u16* __restrict__ rwh, const u16* __restrict__ rwl,
        const float* __restrict__ regb, float* __restrict__ hid){
  __shared__ u16 ash[64*264];
  __shared__ u16 asl[64*264];
  int tid = threadIdx.x;
  int lane = tid & 63, wv = tid >> 6;
  int lr = lane & 15, lg = lane >> 4;
  int tb = blockIdx.x * 64;
  for (int c = tid; c < 2048; c += 256){
    int r = c >> 5, cc = c & 31;
    *(uint4*)(&ash[r*264 + cc*8]) = *(const uint4*)(xh + (size_t)(tb+r)*256 + cc*8);
    *(uint4*)(&asl[r*264 + cc*8]) = *(const uint4*)(xl + (size_t)(tb+r)*256 + cc*8);
  }
  __syncthreads();
  f32x4 acc[4][4];
  #pragma unroll
  for (int mf=0;mf<4;++mf)
    #pragma unroll
    for (int nf=0;nf<4;++nf) acc[mf][nf] = (f32x4){0.f,0.f,0.f,0.f};

  const u16* bhb = rwh + (size_t)wv*64*256;
  const u16* blb = rwl + (size_t)wv*64*256;
  #pragma unroll
  for (int kt=0;kt<8;++kt){
    bf16x8 ah[4], al[4], bh[4], bl[4];
    #pragma unroll
    for (int nf=0;nf<4;++nf){
      bh[nf] = *(const bf16x8*)(bhb + (size_t)(nf*16+lr)*256 + kt*32 + lg*8);
      bl[nf] = *(const bf16x8*)(blb + (size_t)(nf*16+lr)*256 + kt*32 + lg*8);
    }
    #pragma unroll
    for (int mf=0;mf<4;++mf){
      ah[mf] = *(const bf16x8*)(&ash[(mf*16+lr)*264 + kt*32 + lg*8]);
      al[mf] = *(const bf16x8*)(&asl[(mf*16+lr)*264 + kt*32 + lg*8]);
    }
    #pragma unroll
    for (int mf=0;mf<4;++mf)
      #pragma unroll
      for (int nf=0;nf<4;++nf){
        acc[mf][nf] = MFMA(ah[mf], bh[nf], acc[mf][nf]);
        acc[mf][nf] = MFMA(al[mf], bh[nf], acc[mf][nf]);
        acc[mf][nf] = MFMA(ah[mf], bl[nf], acc[mf][nf]);
      }
  }
  int b = tb >> 12;
  #pragma unroll
  for (int mf=0;mf<4;++mf)
    #pragma unroll
    for (int nf=0;nf<4;++nf){
      int j = wv*64 + nf*16 + lr;
      float rbv = regb[b*256 + j];
      #pragma unroll
      for (int r=0;r<4;++r){
        int t = tb + mf*16 + lg*4 + r;
        float v = acc[mf][nf][r] + rbv;
        hid[(size_t)t*256 + j] = v/(1.f+__expf(-v));
      }
    }
}

// ---------- logits + top2 + gates + aux partials ----------
__global__ __launch_bounds__(256) void k_logits(const float* __restrict__ hid,
        const float* __restrict__ rw2, const float* __restrict__ rb2,
        float* __restrict__ selw, float* __restrict__ partials){
  __shared__ float psum[6], pcnt[6];
  int tid = threadIdx.x;
  if (tid < 6){ psum[tid]=0.f; pcnt[tid]=0.f; }
  __syncthreads();
  int lane = tid & 63;
  int lr = lane & 15, lg = lane >> 4;
  int t = blockIdx.x*16 + (tid>>6)*4 + lg;
  float lacc[6] = {0.f,0.f,0.f,0.f,0.f,0.f};
  const float4* hp = (const float4*)(hid + (size_t)t*256);
  #pragma unroll
  for (int p=0;p<4;++p){
    float4 h4 = hp[p*16 + lr];
    float hv[4] = {h4.x,h4.y,h4.z,h4.w};
    int j0 = (p*16+lr)*4;
    #pragma unroll
    for (int q=0;q<4;++q)
      #pragma unroll
      for (int e=0;e<6;++e) lacc[e] += hv[q]*rw2[(j0+q)*6+e];
  }
  #pragma unroll
  for (int m=1;m<16;m<<=1)
    #pragma unroll
    for (int e=0;e<6;++e) lacc[e] += __shfl_xor(lacc[e], m);
  if (lr == 0){
    float lgv[6];
    #pragma unroll
    for (int e=0;e<6;++e) lgv[e] = lacc[e] + rb2[e];
    int i0=0; float v0=lgv[0];
    #pragma unroll
    for (int e=1;e<6;++e) if (lgv[e] > v0){ v0=lgv[e]; i0=e; }
    int i1=-1; float v1=-1e30f;
    #pragma unroll
    for (int e=0;e<6;++e) if (e!=i0 && lgv[e] > v1){ v1=lgv[e]; i1=e; }
    float ex = expf(v1-v0);
    float w0 = 1.f/(1.f+ex), w1 = ex/(1.f+ex);
    #pragma unroll
    for (int e=0;e<6;++e) selw[(size_t)t*6+e] = (e==i0)? w0 : (e==i1)? w1 : 0.f;
    float ps=0.f, p[6];
    #pragma unroll
    for (int e=0;e<6;++e){ p[e]=expf(lgv[e]-v0); ps+=p[e]; }
    float rinv = 1.f/ps;
    #pragma unroll
    for (int e=0;e<6;++e) atomicAdd(&psum[e], p[e]*rinv);
    atomicAdd(&pcnt[i0], 1.f);
  }
  __syncthreads();
  if (tid < 6){
    partials[blockIdx.x*12 + tid] = psum[tid];
    partials[blockIdx.x*12 + 6 + tid] = pcnt[tid];
  }
}

__global__ __launch_bounds__(256) void k_aux(const float* __restrict__ partials, float* __restrict__ outp){
  __shared__ float a[12];
  int tid = threadIdx.x;
  if (tid < 12) a[tid] = 0.f;
  __syncthreads();
  int col = tid & 15, seg = tid >> 4;
  if (col < 12){
    float s = 0.f;
    for (int i=seg; i<2048; i+=16) s += partials[i*12+col];
    atomicAdd(&a[col], s);
  }
  __syncthreads();
  if (tid==0){
    float aux=0.f;
    #pragma unroll
    for (int e=0;e<6;++e) aux += a[e]*a[6+e];
    aux *= 0.01f*6.f/(32768.f*32768.f);
    outp[8388608] = aux;
  }
}

// ---------- fused all-expert MLP v5: slot-major LDS, coalesced reg-direct weights ----------
// 64-token tiles, 512 blocks, 8 waves, 2 blocks/CU. No K-loop barriers.
// LDS (u16): xs cells [s=0..31][tok=0..63] 16B each -> u16 idx = s*512 + tok*8   (32 KB)
//            hs same layout at +16384                                            (32 KB)
__global__ __launch_bounds__(512,4) void k_experts(const u16* __restrict__ xh,
        const u16* __restrict__ w1t2, const u16* __restrict__ w2t2,
        const float* __restrict__ b1g, const float* __restrict__ b2g,
        const float* __restrict__ selw, const float* __restrict__ xg,
        float* __restrict__ outp){
  __shared__ u16 lds[32768];
  int tid = threadIdx.x;
  int lane = tid & 63, wv = tid >> 6;
  int l31 = lane & 31, l5 = lane >> 5;
  int tb = blockIdx.x * 64;

  // stage xs: linear LDS dest (slot-major), row-gathered global source
  #pragma unroll
  for (int it=0; it<4; ++it){
    int gcell = it*512 + tid;
    int s = gcell >> 6, row = gcell & 63;
    gll16(xh + (size_t)(tb+row)*256 + s*8, lds + gcell*8);
  }
  float gw[2][6];
  #pragma unroll
  for (int tt=0;tt<2;++tt){
    int t = tb + tt*32 + l31;
    #pragma unroll
    for (int e=0;e<6;++e) gw[tt][e] = selw[(size_t)t*6 + e];
  }
  __syncthreads();

  f32x16 oacc0 = (f32x16)(0.f), oacc1 = (f32x16)(0.f);

  for (int e=0;e<6;++e){
    #pragma unroll
    for (int hh=0;hh<2;++hh){
      // ---- GEMM1: wave owns 32 h-rows (hh*256 + wv*32), K=256, weights reg-direct ----
      f32x16 a1t0 = (f32x16)(0.f), a1t1 = (f32x16)(0.f);
      const u16* w1b = w1t2 + (size_t)e*131072 + (size_t)(hh*256 + wv*32)*16 + l31*16 + l5*8;
      #pragma unroll
      for (int ks=0;ks<16;++ks){
        bf16x8 af  = *(const bf16x8*)(w1b + ks*8192);
        bf16x8 bx0 = *(const bf16x8*)&lds[(ks*2+l5)*512 + l31*8];
        bf16x8 bx1 = *(const bf16x8*)&lds[(ks*2+l5)*512 + (l31+32)*8];
        a1t0 = MFMA32(af, bx0, a1t0);
        a1t1 = MFMA32(af, bx1, a1t1);
      }
      __syncthreads();   // previous hs readers done
      // ---- epilogue: bias + silu -> hs (slot-major) ----
      #pragma unroll
      for (int rq=0;rq<4;++rq){
        float4 b4 = *(const float4*)(b1g + (size_t)e*512 + hh*256 + wv*32 + rq*8 + l5*4);
        float bb[4] = {b4.x,b4.y,b4.z,b4.w};
        float sv0[4], sv1[4];
        #pragma unroll
        for (int q=0;q<4;++q){
          float v0 = a1t0[rq*4+q] + bb[q];
          float v1 = a1t1[rq*4+q] + bb[q];
          sv0[q] = v0/(1.f+__expf(-v0));
          sv1[q] = v1/(1.f+__expf(-v1));
        }
        unsigned p00 = (unsigned)f2bf(sv0[0]) | ((unsigned)f2bf(sv0[1])<<16);
        unsigned p01 = (unsigned)f2bf(sv0[2]) | ((unsigned)f2bf(sv0[3])<<16);
        unsigned p10 = (unsigned)f2bf(sv1[0]) | ((unsigned)f2bf(sv1[1])<<16);
        unsigned p11 = (unsigned)f2bf(sv1[2]) | ((unsigned)f2bf(sv1[3])<<16);
        int sbase = 16384 + (wv*4+rq)*512 + l5*4;
        *(uint2*)&lds[sbase + l31*8]      = make_uint2(p00,p01);
        *(uint2*)&lds[sbase + (l31+32)*8] = make_uint2(p10,p11);
      }
      __syncthreads();   // hs ready
      // ---- GEMM2: wave owns 32 d-rows, K = this h-half (256), weights reg-direct ----
      f32x16 a2t0 = (f32x16)(0.f), a2t1 = (f32x16)(0.f);
      const u16* w2b = w2t2 + (size_t)e*131072 + (size_t)(hh*16)*4096 + (size_t)(wv*32)*16 + l31*16 + l5*8;
      #pragma unroll
      for (int ks=0;ks<16;++ks){
        bf16x8 wf = *(const bf16x8*)(w2b + ks*4096);
        bf16x8 h0 = *(const bf16x8*)&lds[16384 + (ks*2+l5)*512 + l31*8];
        bf16x8 h1 = *(const bf16x8*)&lds[16384 + (ks*2+l5)*512 + (l31+32)*8];
        a2t0 = MFMA32(wf, h0, a2t0);
        a2t1 = MFMA32(wf, h1, a2t1);
      }
      // ---- fold into gated accumulator ----
      float g0 = gw[0][e], g1 = gw[1][e];
      #pragma unroll
      for (int r=0;r<16;++r){ oacc0[r] += g0*a2t0[r]; oacc1[r] += g1*a2t1[r]; }
      if (hh==1){
        #pragma unroll
        for (int rq=0;rq<4;++rq){
          float4 b4 = *(const float4*)(b2g + (size_t)e*256 + wv*32 + rq*8 + l5*4);
          float bb[4] = {b4.x,b4.y,b4.z,b4.w};
          #pragma unroll
          for (int q=0;q<4;++q){
            oacc0[rq*4+q] += g0*bb[q];
            oacc1[rq*4+q] += g1*bb[q];
          }
        }
      }
    }
  }
  // ---- residual + store ----
  #pragma unroll
  for (int rq=0;rq<4;++rq){
    int d = wv*32 + rq*8 + l5*4;
    int t0 = tb + l31, t1 = tb + 32 + l31;
    float4 x0 = *(const float4*)(xg + (size_t)t0*256 + d);
    float4 x1 = *(const float4*)(xg + (size_t)t1*256 + d);
    float4 o0, o1;
    o0.x = x0.x + oacc0[rq*4+0]; o0.y = x0.y + oacc0[rq*4+1];
    o0.z = x0.z + oacc0[rq*4+2]; o0.w = x0.w + oacc0[rq*4+3];
    o1.x = x1.x + oacc1[rq*4+0]; o1.y = x1.y + oacc1[rq*4+1];
    o1.z = x1.z + oacc1[rq*4+2]; o1.w = x1.w + oacc1[rq*4+3];
    *(float4*)(outp + (size_t)t0*256 + d) = o0;
    *(float4*)(outp + (size_t)t1*256 + d) = o1;
  }
}

extern "C" void kernel_launch(void* const* d_in, const int* in_sizes, int n_in,
                              void* d_out, int out_size, void* d_ws, size_t ws_size,
                              hipStream_t stream){
  const float* x      = (const float*)d_in[0];
  const float* regime = (const float*)d_in[1];
  const float* ln_g   = (const float*)d_in[2];
  const float* ln_b   = (const float*)d_in[3];
  const float* w1     = (const float*)d_in[4];
  const float* b1     = (const float*)d_in[5];
  const float* w2     = (const float*)d_in[6];
  const float* b2     = (const float*)d_in[7];
  const float* rw1    = (const float*)d_in[8];
  const float* rb1    = (const float*)d_in[9];
  const float* rw2    = (const float*)d_in[10];
  const float* rb2    = (const float*)d_in[11];
  float* outp = (float*)d_out;
  char* ws = (char*)d_ws;

  u16*   w1t2 = (u16*)(ws + 0);          // 1,572,864
  u16*   w2t2 = (u16*)(ws + 1572864);    // 1,572,864
  u16*   rwh  = (u16*)(ws + 3145728);    // 131,072
  u16*   rwl  = (u16*)(ws + 3276800);    // 131,072
  float* regb = (float*)(ws + 3407872);  // 8,192
  u16*   xh   = (u16*)(ws + 3416064);    // 16,777,216
  u16*   xl   = (u16*)(ws + 20193280);   // 16,777,216 (dead after k_router)
  float* part = (float*)(ws + 20193280); // 98,304 — overlays xl, written after router
  float* hid  = (float*)(ws + 36970496); // 33,554,432
  float* selw = (float*)(ws + 70524928); // 786,432

  k_transpose<<<384,256,0,stream>>>(w1, w2, w1t2, w2t2);
  k_prep_rw1<<<264,256,0,stream>>>(rw1, rb1, regime, rwh, rwl, regb);
  k_ln<<<8192,256,0,stream>>>(x, ln_g, ln_b, xh, xl);
  k_router<<<512,256,0,stream>>>(xh, xl, rwh, rwl, regb, hid);
  k_logits<<<2048,256,0,stream>>>(hid, rw2, rb2, selw, part);
  k_aux<<<1,256,0,stream>>>(part, outp);
  k_experts<<<512,512,0,stream>>>(xh, w1t2, w2t2, b1, b2, selw, x, outp);
}

// Round 8
// 381.233 us; speedup vs baseline: 1.2173x; 1.2173x over previous
//
#include <hip/hip_runtime.h>
#include <cmath>

typedef unsigned short u16;
typedef __attribute__((ext_vector_type(8))) short bf16x8;
typedef __attribute__((ext_vector_type(4))) float f32x4;
typedef __attribute__((ext_vector_type(16))) float f32x16;

#define MFMA(a,b,c)   __builtin_amdgcn_mfma_f32_16x16x32_bf16((a),(b),(c),0,0,0)
#define MFMA32(a,b,c) __builtin_amdgcn_mfma_f32_32x32x16_bf16((a),(b),(c),0,0,0)

__device__ __forceinline__ float bf2f(u16 u){ return __uint_as_float(((unsigned)u)<<16); }
__device__ __forceinline__ u16 f2bf(float f){
  unsigned x = __float_as_uint(f);
  return (u16)((x + 0x7FFFu + ((x>>16)&1u)) >> 16);
}

__device__ __forceinline__ void gll16(const u16* g, u16* l){
  __builtin_amdgcn_global_load_lds((const __attribute__((address_space(1))) unsigned*)g,
                                   (__attribute__((address_space(3))) unsigned*)l, 16, 0, 0);
}

// ---------- prep: transpose + re-layout to slab-contiguous bf16 ----------
// w1 (E,D,H) -> w1t2[e][kd=d>>4][h][d&15]  (slab (e,kd) = 512 rows x 32B = 16KB)
// w2 (E,H,D) -> w2t2[e][kh=h>>4][d][h&15]  (slab (e,kh) = 256 rows x 32B = 8KB)
__global__ __launch_bounds__(256) void k_transpose(const float* __restrict__ w1,
        const float* __restrict__ w2, u16* __restrict__ w1t2, u16* __restrict__ w2t2){
  __shared__ u16 t[64][66];
  int b = blockIdx.x;
  int c0 = threadIdx.x & 63, r0 = threadIdx.x >> 6;
  if (b < 192){            // w1: src (D=256 x H=512)
    int e = b >> 5, tl = b & 31;
    int tr = (tl >> 3) << 6, tc = (tl & 7) << 6;
    const float* src = w1 + (size_t)e*131072;
    u16* dst = w1t2 + (size_t)e*131072;
    #pragma unroll
    for (int i=0;i<16;++i){
      int r = r0 + i*4;
      t[c0][r] = f2bf(src[(size_t)(tr+r)*512 + tc + c0]);   // coalesced along H
    }
    __syncthreads();
    #pragma unroll
    for (int i=0;i<16;++i){
      int cc = r0 + i*4;
      int h = tc + cc, d = tr + c0;
      dst[(size_t)((d>>4)*512 + h)*16 + (d&15)] = t[cc][c0];
    }
  } else {                 // w2: src (H=512 x D=256)
    int bb = b - 192;
    int e = bb >> 5, tl = bb & 31;
    int tr = (tl >> 2) << 6, tc = (tl & 3) << 6;
    const float* src = w2 + (size_t)e*131072;
    u16* dst = w2t2 + (size_t)e*131072;
    #pragma unroll
    for (int i=0;i<16;++i){
      int r = r0 + i*4;
      t[c0][r] = f2bf(src[(size_t)(tr+r)*256 + tc + c0]);   // coalesced along D
    }
    __syncthreads();
    #pragma unroll
    for (int i=0;i<16;++i){
      int cc = r0 + i*4;
      int d = tc + cc, h = tr + c0;
      dst[(size_t)((h>>4)*256 + d)*16 + (h&15)] = t[cc][c0];
    }
  }
}

// rw1 (261,256): first 256 rows -> [j][d] hi/lo bf16; rows 256..260 + rb1 folded into regb[b][j].
__global__ void k_prep_rw1(const float* __restrict__ rw1, const float* __restrict__ rb1,
                           const float* __restrict__ regime,
                           u16* __restrict__ rwh, u16* __restrict__ rwl,
                           float* __restrict__ regb){
  int idx = blockIdx.x*256 + threadIdx.x;  // 65536 + 2048 total
  if (idx < 65536){
    int dd = idx & 255, j = idx >> 8;
    float w = rw1[dd*256 + j];
    u16 hi = f2bf(w);
    rwh[idx] = hi;
    rwl[idx] = f2bf(w - bf2f(hi));
  } else {
    int i = idx - 65536; int j = i & 255, b = i >> 8;
    float v = rb1[j];
    #pragma unroll
    for (int r=0;r<5;++r) v += regime[b*5+r]*rw1[(256+r)*256 + j];
    regb[b*256 + j] = v;
  }
}

// ---------- LayerNorm: x -> xn hi/lo bf16 (wave per token) ----------
__global__ __launch_bounds__(256) void k_ln(const float* __restrict__ x,
        const float* __restrict__ g, const float* __restrict__ bta,
        u16* __restrict__ xh, u16* __restrict__ xl){
  int wv = threadIdx.x >> 6, lane = threadIdx.x & 63;
  int t = blockIdx.x*4 + wv;
  float4 v = ((const float4*)(x + (size_t)t*256))[lane];
  float s  = v.x+v.y+v.z+v.w;
  float ss = v.x*v.x+v.y*v.y+v.z*v.z+v.w*v.w;
  #pragma unroll
  for (int m=32;m>=1;m>>=1){ s += __shfl_xor(s,m); ss += __shfl_xor(ss,m); }
  float mu  = s*(1.f/256.f);
  float var = ss*(1.f/256.f) - mu*mu;
  float inv = 1.f / sqrtf(var + 1e-5f);
  float4 gv = ((const float4*)g)[lane];
  float4 bv = ((const float4*)bta)[lane];
  float xv[4] = {v.x,v.y,v.z,v.w};
  float gg[4] = {gv.x,gv.y,gv.z,gv.w};
  float bb[4] = {bv.x,bv.y,bv.z,bv.w};
  u16 hh[4], ll[4];
  #pragma unroll
  for (int q=0;q<4;++q){
    float xn = (xv[q]-mu)*inv*gg[q] + bb[q];
    u16 h = f2bf(xn);
    hh[q] = h;
    ll[q] = f2bf(xn - bf2f(h));
  }
  ((ushort4*)(xh + (size_t)t*256))[lane] = make_ushort4(hh[0],hh[1],hh[2],hh[3]);
  ((ushort4*)(xl + (size_t)t*256))[lane] = make_ushort4(ll[0],ll[1],ll[2],ll[3]);
}

// ---------- router GEMM (hi/lo MFMA, weight frags direct from L2) ----------
__global__ __launch_bounds__(256,2) void k_router(const u16* __restrict__ xh, const u16* __restrict__ xl,
        const u16* __restrict__ rwh, const u16* __restrict__ rwl,
        const float* __restrict__ regb, float* __restrict__ hid){
  __shared__ u16 ash[64*264];
  __shared__ u16 asl[64*264];
  int tid = threadIdx.x;
  int lane = tid & 63, wv = tid >> 6;
  int lr = lane & 15, lg = lane >> 4;
  int tb = blockIdx.x * 64;
  for (int c = tid; c < 2048; c += 256){
    int r = c >> 5, cc = c & 31;
    *(uint4*)(&ash[r*264 + cc*8]) = *(const uint4*)(xh + (size_t)(tb+r)*256 + cc*8);
    *(uint4*)(&asl[r*264 + cc*8]) = *(const uint4*)(xl + (size_t)(tb+r)*256 + cc*8);
  }
  __syncthreads();
  f32x4 acc[4][4];
  #pragma unroll
  for (int mf=0;mf<4;++mf)
    #pragma unroll
    for (int nf=0;nf<4;++nf) acc[mf][nf] = (f32x4){0.f,0.f,0.f,0.f};

  const u16* bhb = rwh + (size_t)wv*64*256;
  const u16* blb = rwl + (size_t)wv*64*256;
  #pragma unroll
  for (int kt=0;kt<8;++kt){
    bf16x8 ah[4], al[4], bh[4], bl[4];
    #pragma unroll
    for (int nf=0;nf<4;++nf){
      bh[nf] = *(const bf16x8*)(bhb + (size_t)(nf*16+lr)*256 + kt*32 + lg*8);
      bl[nf] = *(const bf16x8*)(blb + (size_t)(nf*16+lr)*256 + kt*32 + lg*8);
    }
    #pragma unroll
    for (int mf=0;mf<4;++mf){
      ah[mf] = *(const bf16x8*)(&ash[(mf*16+lr)*264 + kt*32 + lg*8]);
      al[mf] = *(const bf16x8*)(&asl[(mf*16+lr)*264 + kt*32 + lg*8]);
    }
    #pragma unroll
    for (int mf=0;mf<4;++mf)
      #pragma unroll
      for (int nf=0;nf<4;++nf){
        acc[mf][nf] = MFMA(ah[mf], bh[nf], acc[mf][nf]);
        acc[mf][nf] = MFMA(al[mf], bh[nf], acc[mf][nf]);
        acc[mf][nf] = MFMA(ah[mf], bl[nf], acc[mf][nf]);
      }
  }
  int b = tb >> 12;
  #pragma unroll
  for (int mf=0;mf<4;++mf)
    #pragma unroll
    for (int nf=0;nf<4;++nf){
      int j = wv*64 + nf*16 + lr;
      float rbv = regb[b*256 + j];
      #pragma unroll
      for (int r=0;r<4;++r){
        int t = tb + mf*16 + lg*4 + r;
        float v = acc[mf][nf][r] + rbv;
        hid[(size_t)t*256 + j] = v/(1.f+__expf(-v));
      }
    }
}

// ---------- logits + top2 + gates + aux partials ----------
__global__ __launch_bounds__(256) void k_logits(const float* __restrict__ hid,
        const float* __restrict__ rw2, const float* __restrict__ rb2,
        float* __restrict__ selw, float* __restrict__ partials){
  __shared__ float psum[6], pcnt[6];
  int tid = threadIdx.x;
  if (tid < 6){ psum[tid]=0.f; pcnt[tid]=0.f; }
  __syncthreads();
  int lane = tid & 63;
  int lr = lane & 15, lg = lane >> 4;
  int t = blockIdx.x*16 + (tid>>6)*4 + lg;
  float lacc[6] = {0.f,0.f,0.f,0.f,0.f,0.f};
  const float4* hp = (const float4*)(hid + (size_t)t*256);
  #pragma unroll
  for (int p=0;p<4;++p){
    float4 h4 = hp[p*16 + lr];
    float hv[4] = {h4.x,h4.y,h4.z,h4.w};
    int j0 = (p*16+lr)*4;
    #pragma unroll
    for (int q=0;q<4;++q)
      #pragma unroll
      for (int e=0;e<6;++e) lacc[e] += hv[q]*rw2[(j0+q)*6+e];
  }
  #pragma unroll
  for (int m=1;m<16;m<<=1)
    #pragma unroll
    for (int e=0;e<6;++e) lacc[e] += __shfl_xor(lacc[e], m);
  if (lr == 0){
    float lgv[6];
    #pragma unroll
    for (int e=0;e<6;++e) lgv[e] = lacc[e] + rb2[e];
    int i0=0; float v0=lgv[0];
    #pragma unroll
    for (int e=1;e<6;++e) if (lgv[e] > v0){ v0=lgv[e]; i0=e; }
    int i1=-1; float v1=-1e30f;
    #pragma unroll
    for (int e=0;e<6;++e) if (e!=i0 && lgv[e] > v1){ v1=lgv[e]; i1=e; }
    float ex = expf(v1-v0);
    float w0 = 1.f/(1.f+ex), w1 = ex/(1.f+ex);
    #pragma unroll
    for (int e=0;e<6;++e) selw[(size_t)t*6+e] = (e==i0)? w0 : (e==i1)? w1 : 0.f;
    float ps=0.f, p[6];
    #pragma unroll
    for (int e=0;e<6;++e){ p[e]=expf(lgv[e]-v0); ps+=p[e]; }
    float rinv = 1.f/ps;
    #pragma unroll
    for (int e=0;e<6;++e) atomicAdd(&psum[e], p[e]*rinv);
    atomicAdd(&pcnt[i0], 1.f);
  }
  __syncthreads();
  if (tid < 6){
    partials[blockIdx.x*12 + tid] = psum[tid];
    partials[blockIdx.x*12 + 6 + tid] = pcnt[tid];
  }
}

__global__ __launch_bounds__(256) void k_aux(const float* __restrict__ partials, float* __restrict__ outp){
  __shared__ float a[12];
  int tid = threadIdx.x;
  if (tid < 12) a[tid] = 0.f;
  __syncthreads();
  int col = tid & 15, seg = tid >> 4;
  if (col < 12){
    float s = 0.f;
    for (int i=seg; i<2048; i+=16) s += partials[i*12+col];
    atomicAdd(&a[col], s);
  }
  __syncthreads();
  if (tid==0){
    float aux=0.f;
    #pragma unroll
    for (int e=0;e<6;++e) aux += a[e]*a[6+e];
    aux *= 0.01f*6.f/(32768.f*32768.f);
    outp[8388608] = aux;
  }
}

// ---------- fused all-expert MLP v5b: slot-major LDS, reg-direct weights, no spill ----------
// 64-token tiles, 512 blocks, 8 waves, 2 blocks/CU. No K-loop barriers.
// LDS (u16): xs cells [s=0..31][tok=0..63] 16B each -> u16 idx = s*512 + tok*8   (32 KB)
//            hs same layout at +16384                                            (32 KB)
// launch_bounds (512,2): 128-VGPR budget — (512,4) forced 64 VGPR and spilled (r7).
__global__ __launch_bounds__(512,2) void k_experts(const u16* __restrict__ xh,
        const u16* __restrict__ w1t2, const u16* __restrict__ w2t2,
        const float* __restrict__ b1g, const float* __restrict__ b2g,
        const float* __restrict__ selw, const float* __restrict__ xg,
        float* __restrict__ outp){
  __shared__ u16 lds[32768];
  int tid = threadIdx.x;
  int lane = tid & 63, wv = tid >> 6;
  int l31 = lane & 31, l5 = lane >> 5;
  int tb = blockIdx.x * 64;

  // stage xs: linear LDS dest (slot-major), row-gathered global source
  #pragma unroll
  for (int it=0; it<4; ++it){
    int gcell = it*512 + tid;
    int s = gcell >> 6, row = gcell & 63;
    gll16(xh + (size_t)(tb+row)*256 + s*8, lds + gcell*8);
  }
  float gw[2][6];
  #pragma unroll
  for (int tt=0;tt<2;++tt){
    int t = tb + tt*32 + l31;
    #pragma unroll
    for (int e=0;e<6;++e) gw[tt][e] = selw[(size_t)t*6 + e];
  }
  __syncthreads();

  f32x16 oacc0 = (f32x16)(0.f), oacc1 = (f32x16)(0.f);

  for (int e=0;e<6;++e){
    #pragma unroll
    for (int hh=0;hh<2;++hh){
      // ---- GEMM1: wave owns 32 h-rows (hh*256 + wv*32), K=256, weights reg-direct ----
      f32x16 a1t0 = (f32x16)(0.f), a1t1 = (f32x16)(0.f);
      const u16* w1b = w1t2 + (size_t)e*131072 + (size_t)(hh*256 + wv*32)*16 + l31*16 + l5*8;
      #pragma unroll
      for (int ks=0;ks<16;++ks){
        bf16x8 af  = *(const bf16x8*)(w1b + ks*8192);
        bf16x8 bx0 = *(const bf16x8*)&lds[(ks*2+l5)*512 + l31*8];
        bf16x8 bx1 = *(const bf16x8*)&lds[(ks*2+l5)*512 + (l31+32)*8];
        a1t0 = MFMA32(af, bx0, a1t0);
        a1t1 = MFMA32(af, bx1, a1t1);
      }
      __syncthreads();   // previous hs readers done
      // ---- epilogue: bias + silu -> hs (slot-major) ----
      #pragma unroll
      for (int rq=0;rq<4;++rq){
        float4 b4 = *(const float4*)(b1g + (size_t)e*512 + hh*256 + wv*32 + rq*8 + l5*4);
        float bb[4] = {b4.x,b4.y,b4.z,b4.w};
        float sv0[4], sv1[4];
        #pragma unroll
        for (int q=0;q<4;++q){
          float v0 = a1t0[rq*4+q] + bb[q];
          float v1 = a1t1[rq*4+q] + bb[q];
          sv0[q] = v0/(1.f+__expf(-v0));
          sv1[q] = v1/(1.f+__expf(-v1));
        }
        unsigned p00 = (unsigned)f2bf(sv0[0]) | ((unsigned)f2bf(sv0[1])<<16);
        unsigned p01 = (unsigned)f2bf(sv0[2]) | ((unsigned)f2bf(sv0[3])<<16);
        unsigned p10 = (unsigned)f2bf(sv1[0]) | ((unsigned)f2bf(sv1[1])<<16);
        unsigned p11 = (unsigned)f2bf(sv1[2]) | ((unsigned)f2bf(sv1[3])<<16);
        int sbase = 16384 + (wv*4+rq)*512 + l5*4;
        *(uint2*)&lds[sbase + l31*8]      = make_uint2(p00,p01);
        *(uint2*)&lds[sbase + (l31+32)*8] = make_uint2(p10,p11);
      }
      __syncthreads();   // hs ready
      // ---- GEMM2: wave owns 32 d-rows, K = this h-half (256), weights reg-direct ----
      f32x16 a2t0 = (f32x16)(0.f), a2t1 = (f32x16)(0.f);
      const u16* w2b = w2t2 + (size_t)e*131072 + (size_t)(hh*16)*4096 + (size_t)(wv*32)*16 + l31*16 + l5*8;
      #pragma unroll
      for (int ks=0;ks<16;++ks){
        bf16x8 wf = *(const bf16x8*)(w2b + ks*4096);
        bf16x8 h0 = *(const bf16x8*)&lds[16384 + (ks*2+l5)*512 + l31*8];
        bf16x8 h1 = *(const bf16x8*)&lds[16384 + (ks*2+l5)*512 + (l31+32)*8];
        a2t0 = MFMA32(wf, h0, a2t0);
        a2t1 = MFMA32(wf, h1, a2t1);
      }
      // ---- fold into gated accumulator ----
      float g0 = gw[0][e], g1 = gw[1][e];
      #pragma unroll
      for (int r=0;r<16;++r){ oacc0[r] += g0*a2t0[r]; oacc1[r] += g1*a2t1[r]; }
      if (hh==1){
        #pragma unroll
        for (int rq=0;rq<4;++rq){
          float4 b4 = *(const float4*)(b2g + (size_t)e*256 + wv*32 + rq*8 + l5*4);
          float bb[4] = {b4.x,b4.y,b4.z,b4.w};
          #pragma unroll
          for (int q=0;q<4;++q){
            oacc0[rq*4+q] += g0*bb[q];
            oacc1[rq*4+q] += g1*bb[q];
          }
        }
      }
    }
  }
  // ---- residual + store ----
  #pragma unroll
  for (int rq=0;rq<4;++rq){
    int d = wv*32 + rq*8 + l5*4;
    int t0 = tb + l31, t1 = tb + 32 + l31;
    float4 x0 = *(const float4*)(xg + (size_t)t0*256 + d);
    float4 x1 = *(const float4*)(xg + (size_t)t1*256 + d);
    float4 o0, o1;
    o0.x = x0.x + oacc0[rq*4+0]; o0.y = x0.y + oacc0[rq*4+1];
    o0.z = x0.z + oacc0[rq*4+2]; o0.w = x0.w + oacc0[rq*4+3];
    o1.x = x1.x + oacc1[rq*4+0]; o1.y = x1.y + oacc1[rq*4+1];
    o1.z = x1.z + oacc1[rq*4+2]; o1.w = x1.w + oacc1[rq*4+3];
    *(float4*)(outp + (size_t)t0*256 + d) = o0;
    *(float4*)(outp + (size_t)t1*256 + d) = o1;
  }
}

extern "C" void kernel_launch(void* const* d_in, const int* in_sizes, int n_in,
                              void* d_out, int out_size, void* d_ws, size_t ws_size,
                              hipStream_t stream){
  const float* x      = (const float*)d_in[0];
  const float* regime = (const float*)d_in[1];
  const float* ln_g   = (const float*)d_in[2];
  const float* ln_b   = (const float*)d_in[3];
  const float* w1     = (const float*)d_in[4];
  const float* b1     = (const float*)d_in[5];
  const float* w2     = (const float*)d_in[6];
  const float* b2     = (const float*)d_in[7];
  const float* rw1    = (const float*)d_in[8];
  const float* rb1    = (const float*)d_in[9];
  const float* rw2    = (const float*)d_in[10];
  const float* rb2    = (const float*)d_in[11];
  float* outp = (float*)d_out;
  char* ws = (char*)d_ws;

  u16*   w1t2 = (u16*)(ws + 0);          // 1,572,864
  u16*   w2t2 = (u16*)(ws + 1572864);    // 1,572,864
  u16*   rwh  = (u16*)(ws + 3145728);    // 131,072
  u16*   rwl  = (u16*)(ws + 3276800);    // 131,072
  float* regb = (float*)(ws + 3407872);  // 8,192
  u16*   xh   = (u16*)(ws + 3416064);    // 16,777,216
  u16*   xl   = (u16*)(ws + 20193280);   // 16,777,216 (dead after k_router)
  float* part = (float*)(ws + 20193280); // 98,304 — overlays xl, written after router
  float* hid  = (float*)(ws + 36970496); // 33,554,432
  float* selw = (float*)(ws + 70524928); // 786,432

  k_transpose<<<384,256,0,stream>>>(w1, w2, w1t2, w2t2);
  k_prep_rw1<<<264,256,0,stream>>>(rw1, rb1, regime, rwh, rwl, regb);
  k_ln<<<8192,256,0,stream>>>(x, ln_g, ln_b, xh, xl);
  k_router<<<512,256,0,stream>>>(xh, xl, rwh, rwl, regb, hid);
  k_logits<<<2048,256,0,stream>>>(hid, rw2, rb2, selw, part);
  k_aux<<<1,256,0,stream>>>(part, outp);
  k_experts<<<512,512,0,stream>>>(xh, w1t2, w2t2, b1, b2, selw, x, outp);
}

// Round 10
// 336.773 us; speedup vs baseline: 1.3780x; 1.1320x over previous
//
#include <hip/hip_runtime.h>
#include <cmath>

typedef unsigned short u16;
typedef __attribute__((ext_vector_type(8))) short bf16x8;
typedef __attribute__((ext_vector_type(4))) float f32x4;
typedef __attribute__((ext_vector_type(16))) float f32x16;

#define MFMA(a,b,c)   __builtin_amdgcn_mfma_f32_16x16x32_bf16((a),(b),(c),0,0,0)
#define MFMA32(a,b,c) __builtin_amdgcn_mfma_f32_32x32x16_bf16((a),(b),(c),0,0,0)

__device__ __forceinline__ float bf2f(u16 u){ return __uint_as_float(((unsigned)u)<<16); }
__device__ __forceinline__ u16 f2bf(float f){
  unsigned x = __float_as_uint(f);
  return (u16)((x + 0x7FFFu + ((x>>16)&1u)) >> 16);
}

__device__ __forceinline__ void gll16(const u16* g, u16* l){
  __builtin_amdgcn_global_load_lds((const __attribute__((address_space(1))) unsigned*)g,
                                   (__attribute__((address_space(3))) unsigned*)l, 16, 0, 0);
}

// ---------- prep: transpose + re-layout to slab-contiguous bf16 ----------
// w1 (E,D,H) -> w1t2[e][kd=d>>4][h][d&15]  (slab (e,kd) = 512 rows x 32B = 16KB)
// w2 (E,H,D) -> w2t2[e][kh=h>>4][d][h&15]  (slab (e,kh) = 256 rows x 32B = 8KB)
__global__ __launch_bounds__(256) void k_transpose(const float* __restrict__ w1,
        const float* __restrict__ w2, u16* __restrict__ w1t2, u16* __restrict__ w2t2){
  __shared__ u16 t[64][66];
  int b = blockIdx.x;
  int c0 = threadIdx.x & 63, r0 = threadIdx.x >> 6;
  if (b < 192){            // w1: src (D=256 x H=512)
    int e = b >> 5, tl = b & 31;
    int tr = (tl >> 3) << 6, tc = (tl & 7) << 6;
    const float* src = w1 + (size_t)e*131072;
    u16* dst = w1t2 + (size_t)e*131072;
    #pragma unroll
    for (int i=0;i<16;++i){
      int r = r0 + i*4;
      t[c0][r] = f2bf(src[(size_t)(tr+r)*512 + tc + c0]);   // coalesced along H
    }
    __syncthreads();
    #pragma unroll
    for (int i=0;i<16;++i){
      int cc = r0 + i*4;
      int h = tc + cc, d = tr + c0;
      dst[(size_t)((d>>4)*512 + h)*16 + (d&15)] = t[cc][c0];
    }
  } else {                 // w2: src (H=512 x D=256)
    int bb = b - 192;
    int e = bb >> 5, tl = bb & 31;
    int tr = (tl >> 2) << 6, tc = (tl & 3) << 6;
    const float* src = w2 + (size_t)e*131072;
    u16* dst = w2t2 + (size_t)e*131072;
    #pragma unroll
    for (int i=0;i<16;++i){
      int r = r0 + i*4;
      t[c0][r] = f2bf(src[(size_t)(tr+r)*256 + tc + c0]);   // coalesced along D
    }
    __syncthreads();
    #pragma unroll
    for (int i=0;i<16;++i){
      int cc = r0 + i*4;
      int d = tc + cc, h = tr + c0;
      dst[(size_t)((h>>4)*256 + d)*16 + (h&15)] = t[cc][c0];
    }
  }
}

// rw1 (261,256): first 256 rows -> [j][d] hi/lo bf16; rows 256..260 + rb1 folded into regb[b][j].
__global__ void k_prep_rw1(const float* __restrict__ rw1, const float* __restrict__ rb1,
                           const float* __restrict__ regime,
                           u16* __restrict__ rwh, u16* __restrict__ rwl,
                           float* __restrict__ regb){
  int idx = blockIdx.x*256 + threadIdx.x;  // 65536 + 2048 total
  if (idx < 65536){
    int dd = idx & 255, j = idx >> 8;
    float w = rw1[dd*256 + j];
    u16 hi = f2bf(w);
    rwh[idx] = hi;
    rwl[idx] = f2bf(w - bf2f(hi));
  } else {
    int i = idx - 65536; int j = i & 255, b = i >> 8;
    float v = rb1[j];
    #pragma unroll
    for (int r=0;r<5;++r) v += regime[b*5+r]*rw1[(256+r)*256 + j];
    regb[b*256 + j] = v;
  }
}

// ---------- LayerNorm: x -> xn hi/lo bf16 (wave per token) ----------
__global__ __launch_bounds__(256) void k_ln(const float* __restrict__ x,
        const float* __restrict__ g, const float* __restrict__ bta,
        u16* __restrict__ xh, u16* __restrict__ xl){
  int wv = threadIdx.x >> 6, lane = threadIdx.x & 63;
  int t = blockIdx.x*4 + wv;
  float4 v = ((const float4*)(x + (size_t)t*256))[lane];
  float s  = v.x+v.y+v.z+v.w;
  float ss = v.x*v.x+v.y*v.y+v.z*v.z+v.w*v.w;
  #pragma unroll
  for (int m=32;m>=1;m>>=1){ s += __shfl_xor(s,m); ss += __shfl_xor(ss,m); }
  float mu  = s*(1.f/256.f);
  float var = ss*(1.f/256.f) - mu*mu;
  float inv = 1.f / sqrtf(var + 1e-5f);
  float4 gv = ((const float4*)g)[lane];
  float4 bv = ((const float4*)bta)[lane];
  float xv[4] = {v.x,v.y,v.z,v.w};
  float gg[4] = {gv.x,gv.y,gv.z,gv.w};
  float bb[4] = {bv.x,bv.y,bv.z,bv.w};
  u16 hh[4], ll[4];
  #pragma unroll
  for (int q=0;q<4;++q){
    float xn = (xv[q]-mu)*inv*gg[q] + bb[q];
    u16 h = f2bf(xn);
    hh[q] = h;
    ll[q] = f2bf(xn - bf2f(h));
  }
  ((ushort4*)(xh + (size_t)t*256))[lane] = make_ushort4(hh[0],hh[1],hh[2],hh[3]);
  ((ushort4*)(xl + (size_t)t*256))[lane] = make_ushort4(ll[0],ll[1],ll[2],ll[3]);
}

// ---------- router GEMM (hi/lo MFMA, weight frags direct from L2) ----------
__global__ __launch_bounds__(256,2) void k_router(const u16* __restrict__ xh, const u16* __restrict__ xl,
        const u16* __restrict__ rwh, const u16* __restrict__ rwl,
        const float* __restrict__ regb, float* __restrict__ hid){
  __shared__ u16 ash[64*264];
  __shared__ u16 asl[64*264];
  int tid = threadIdx.x;
  int lane = tid & 63, wv = tid >> 6;
  int lr = lane & 15, lg = lane >> 4;
  int tb = blockIdx.x * 64;
  for (int c = tid; c < 2048; c += 256){
    int r = c >> 5, cc = c & 31;
    *(uint4*)(&ash[r*264 + cc*8]) = *(const uint4*)(xh + (size_t)(tb+r)*256 + cc*8);
    *(uint4*)(&asl[r*264 + cc*8]) = *(const uint4*)(xl + (size_t)(tb+r)*256 + cc*8);
  }
  __syncthreads();
  f32x4 acc[4][4];
  #pragma unroll
  for (int mf=0;mf<4;++mf)
    #pragma unroll
    for (int nf=0;nf<4;++nf) acc[mf][nf] = (f32x4){0.f,0.f,0.f,0.f};

  const u16* bhb = rwh + (size_t)wv*64*256;
  const u16* blb = rwl + (size_t)wv*64*256;
  #pragma unroll
  for (int kt=0;kt<8;++kt){
    bf16x8 ah[4], al[4], bh[4], bl[4];
    #pragma unroll
    for (int nf=0;nf<4;++nf){
      bh[nf] = *(const bf16x8*)(bhb + (size_t)(nf*16+lr)*256 + kt*32 + lg*8);
      bl[nf] = *(const bf16x8*)(blb + (size_t)(nf*16+lr)*256 + kt*32 + lg*8);
    }
    #pragma unroll
    for (int mf=0;mf<4;++mf){
      ah[mf] = *(const bf16x8*)(&ash[(mf*16+lr)*264 + kt*32 + lg*8]);
      al[mf] = *(const bf16x8*)(&asl[(mf*16+lr)*264 + kt*32 + lg*8]);
    }
    #pragma unroll
    for (int mf=0;mf<4;++mf)
      #pragma unroll
      for (int nf=0;nf<4;++nf){
        acc[mf][nf] = MFMA(ah[mf], bh[nf], acc[mf][nf]);
        acc[mf][nf] = MFMA(al[mf], bh[nf], acc[mf][nf]);
        acc[mf][nf] = MFMA(ah[mf], bl[nf], acc[mf][nf]);
      }
  }
  int b = tb >> 12;
  #pragma unroll
  for (int mf=0;mf<4;++mf)
    #pragma unroll
    for (int nf=0;nf<4;++nf){
      int j = wv*64 + nf*16 + lr;
      float rbv = regb[b*256 + j];
      #pragma unroll
      for (int r=0;r<4;++r){
        int t = tb + mf*16 + lg*4 + r;
        float v = acc[mf][nf][r] + rbv;
        hid[(size_t)t*256 + j] = v/(1.f+__expf(-v));
      }
    }
}

// ---------- logits + top2 + gates + aux partials ----------
__global__ __launch_bounds__(256) void k_logits(const float* __restrict__ hid,
        const float* __restrict__ rw2, const float* __restrict__ rb2,
        float* __restrict__ selw, float* __restrict__ partials){
  __shared__ float psum[6], pcnt[6];
  int tid = threadIdx.x;
  if (tid < 6){ psum[tid]=0.f; pcnt[tid]=0.f; }
  __syncthreads();
  int lane = tid & 63;
  int lr = lane & 15, lg = lane >> 4;
  int t = blockIdx.x*16 + (tid>>6)*4 + lg;
  float lacc[6] = {0.f,0.f,0.f,0.f,0.f,0.f};
  const float4* hp = (const float4*)(hid + (size_t)t*256);
  #pragma unroll
  for (int p=0;p<4;++p){
    float4 h4 = hp[p*16 + lr];
    float hv[4] = {h4.x,h4.y,h4.z,h4.w};
    int j0 = (p*16+lr)*4;
    #pragma unroll
    for (int q=0;q<4;++q)
      #pragma unroll
      for (int e=0;e<6;++e) lacc[e] += hv[q]*rw2[(j0+q)*6+e];
  }
  #pragma unroll
  for (int m=1;m<16;m<<=1)
    #pragma unroll
    for (int e=0;e<6;++e) lacc[e] += __shfl_xor(lacc[e], m);
  if (lr == 0){
    float lgv[6];
    #pragma unroll
    for (int e=0;e<6;++e) lgv[e] = lacc[e] + rb2[e];
    int i0=0; float v0=lgv[0];
    #pragma unroll
    for (int e=1;e<6;++e) if (lgv[e] > v0){ v0=lgv[e]; i0=e; }
    int i1=-1; float v1=-1e30f;
    #pragma unroll
    for (int e=0;e<6;++e) if (e!=i0 && lgv[e] > v1){ v1=lgv[e]; i1=e; }
    float ex = expf(v1-v0);
    float w0 = 1.f/(1.f+ex), w1 = ex/(1.f+ex);
    #pragma unroll
    for (int e=0;e<6;++e) selw[(size_t)t*6+e] = (e==i0)? w0 : (e==i1)? w1 : 0.f;
    float ps=0.f, p[6];
    #pragma unroll
    for (int e=0;e<6;++e){ p[e]=expf(lgv[e]-v0); ps+=p[e]; }
    float rinv = 1.f/ps;
    #pragma unroll
    for (int e=0;e<6;++e) atomicAdd(&psum[e], p[e]*rinv);
    atomicAdd(&pcnt[i0], 1.f);
  }
  __syncthreads();
  if (tid < 6){
    partials[blockIdx.x*12 + tid] = psum[tid];
    partials[blockIdx.x*12 + 6 + tid] = pcnt[tid];
  }
}

__global__ __launch_bounds__(256) void k_aux(const float* __restrict__ partials, float* __restrict__ outp){
  __shared__ float a[12];
  int tid = threadIdx.x;
  if (tid < 12) a[tid] = 0.f;
  __syncthreads();
  int col = tid & 15, seg = tid >> 4;
  if (col < 12){
    float s = 0.f;
    for (int i=seg; i<2048; i+=16) s += partials[i*12+col];
    atomicAdd(&a[col], s);
  }
  __syncthreads();
  if (tid==0){
    float aux=0.f;
    #pragma unroll
    for (int e=0;e<6;++e) aux += a[e]*a[6+e];
    aux *= 0.01f*6.f/(32768.f*32768.f);
    outp[8388608] = aux;
  }
}

// ---------- fused all-expert MLP v6b: 128-token tiles, depth-4 prefetch, hs sized right ----------
// 256 blocks (1/CU), 8 waves. Slot-major LDS (conflict-free):
//   xs [s=0..31][tok=0..127] 16B cells -> u16 idx = s*1024 + tok*8            (64 KB)
//   hs [sh=0..31][tok=0..127] at +32768                                       (64 KB)  <- r9 bug: was 32 KB
//   wsl 768 floats (gates)
__global__ __launch_bounds__(512,2) void k_experts(const u16* __restrict__ xh,
        const u16* __restrict__ w1t2, const u16* __restrict__ w2t2,
        const float* __restrict__ b1g, const float* __restrict__ b2g,
        const float* __restrict__ selw, const float* __restrict__ xg,
        float* __restrict__ outp){
  __shared__ u16 lds[65536];
  __shared__ float wsl[768];
  int tid = threadIdx.x;
  int lane = tid & 63, wv = tid >> 6;
  int l31 = lane & 31, l5 = lane >> 5;
  int tb = blockIdx.x * 128;

  // stage xs: linear LDS dest (slot-major), row-gathered global source
  #pragma unroll
  for (int it=0; it<8; ++it){
    int gcell = it*512 + tid;
    int s = gcell >> 7, tok = gcell & 127;
    gll16(xh + (size_t)(tb+tok)*256 + s*8, lds + gcell*8);
  }
  for (int i=tid;i<768;i+=512) wsl[i] = selw[(size_t)tb*6 + i];
  __syncthreads();

  f32x16 oacc[4];
  #pragma unroll
  for (int tt=0;tt<4;++tt) oacc[tt] = (f32x16)(0.f);

  for (int e=0;e<6;++e){
    #pragma unroll
    for (int hh=0;hh<2;++hh){
      // ---- GEMM1: wave owns 32 h-rows (hh*256 + wv*32), K=256, reg-direct weights ----
      f32x16 a1[4];
      #pragma unroll
      for (int tt=0;tt<4;++tt) a1[tt] = (f32x16)(0.f);
      const u16* w1b = w1t2 + (size_t)e*131072 + (size_t)(hh*256 + wv*32)*16 + l31*16 + l5*8;
      {
        bf16x8 p0 = *(const bf16x8*)(w1b);
        bf16x8 p1 = *(const bf16x8*)(w1b + 8192);
        bf16x8 p2 = *(const bf16x8*)(w1b + 2*8192);
        bf16x8 p3 = *(const bf16x8*)(w1b + 3*8192);
        #pragma unroll
        for (int ks=0; ks<16; ++ks){
          bf16x8 cur = p0; p0 = p1; p1 = p2; p2 = p3;
          if (ks+4 < 16) p3 = *(const bf16x8*)(w1b + (ks+4)*8192);
          #pragma unroll
          for (int tt=0;tt<4;++tt){
            bf16x8 bx = *(const bf16x8*)&lds[(ks*2+l5)*1024 + (tt*32+l31)*8];
            a1[tt] = MFMA32(cur, bx, a1[tt]);
          }
        }
      }
      __syncthreads();   // previous hs readers done
      // ---- epilogue: bias + silu -> hs (slot-major) ----
      #pragma unroll
      for (int rq=0;rq<4;++rq){
        float4 b4 = *(const float4*)(b1g + (size_t)e*512 + hh*256 + wv*32 + rq*8 + l5*4);
        float bb[4] = {b4.x,b4.y,b4.z,b4.w};
        #pragma unroll
        for (int tt=0;tt<4;++tt){
          float sv[4];
          #pragma unroll
          for (int q=0;q<4;++q){
            float v = a1[tt][rq*4+q] + bb[q];
            sv[q] = v/(1.f+__expf(-v));
          }
          unsigned p0 = (unsigned)f2bf(sv[0]) | ((unsigned)f2bf(sv[1])<<16);
          unsigned p1 = (unsigned)f2bf(sv[2]) | ((unsigned)f2bf(sv[3])<<16);
          *(uint2*)&lds[32768 + (wv*4+rq)*1024 + (tt*32+l31)*8 + l5*4] = make_uint2(p0,p1);
        }
      }
      __syncthreads();   // hs ready
      // ---- GEMM2: wave owns 32 d-rows, K = this h-half (256), reg-direct weights ----
      f32x16 a2[4];
      #pragma unroll
      for (int tt=0;tt<4;++tt) a2[tt] = (f32x16)(0.f);
      const u16* w2b = w2t2 + (size_t)e*131072 + (size_t)(hh*16)*4096 + (size_t)(wv*32 + l31)*16 + l5*8;
      {
        bf16x8 p0 = *(const bf16x8*)(w2b);
        bf16x8 p1 = *(const bf16x8*)(w2b + 4096);
        bf16x8 p2 = *(const bf16x8*)(w2b + 2*4096);
        bf16x8 p3 = *(const bf16x8*)(w2b + 3*4096);
        #pragma unroll
        for (int ks=0; ks<16; ++ks){
          bf16x8 cur = p0; p0 = p1; p1 = p2; p2 = p3;
          if (ks+4 < 16) p3 = *(const bf16x8*)(w2b + (ks+4)*4096);
          #pragma unroll
          for (int tt=0;tt<4;++tt){
            bf16x8 hf = *(const bf16x8*)&lds[32768 + (ks*2+l5)*1024 + (tt*32+l31)*8];
            a2[tt] = MFMA32(cur, hf, a2[tt]);
          }
        }
      }
      // ---- fold into gated accumulator ----
      #pragma unroll
      for (int tt=0;tt<4;++tt){
        float g = wsl[(tt*32+l31)*6 + e];
        #pragma unroll
        for (int r=0;r<16;++r) oacc[tt][r] += g*a2[tt][r];
        if (hh==1){
          #pragma unroll
          for (int rq=0;rq<4;++rq){
            float4 b4 = *(const float4*)(b2g + (size_t)e*256 + wv*32 + rq*8 + l5*4);
            oacc[tt][rq*4+0] += g*b4.x;
            oacc[tt][rq*4+1] += g*b4.y;
            oacc[tt][rq*4+2] += g*b4.z;
            oacc[tt][rq*4+3] += g*b4.w;
          }
        }
      }
    }
  }
  // ---- residual + store ----
  #pragma unroll
  for (int tt=0;tt<4;++tt){
    int t = tb + tt*32 + l31;
    #pragma unroll
    for (int rq=0;rq<4;++rq){
      int d = wv*32 + rq*8 + l5*4;
      float4 xv = *(const float4*)(xg + (size_t)t*256 + d);
      float4 o;
      o.x = xv.x + oacc[tt][rq*4+0];
      o.y = xv.y + oacc[tt][rq*4+1];
      o.z = xv.z + oacc[tt][rq*4+2];
      o.w = xv.w + oacc[tt][rq*4+3];
      *(float4*)(outp + (size_t)t*256 + d) = o;
    }
  }
}

extern "C" void kernel_launch(void* const* d_in, const int* in_sizes, int n_in,
                              void* d_out, int out_size, void* d_ws, size_t ws_size,
                              hipStream_t stream){
  const float* x      = (const float*)d_in[0];
  const float* regime = (const float*)d_in[1];
  const float* ln_g   = (const float*)d_in[2];
  const float* ln_b   = (const float*)d_in[3];
  const float* w1     = (const float*)d_in[4];
  const float* b1     = (const float*)d_in[5];
  const float* w2     = (const float*)d_in[6];
  const float* b2     = (const float*)d_in[7];
  const float* rw1    = (const float*)d_in[8];
  const float* rb1    = (const float*)d_in[9];
  const float* rw2    = (const float*)d_in[10];
  const float* rb2    = (const float*)d_in[11];
  float* outp = (float*)d_out;
  char* ws = (char*)d_ws;

  u16*   w1t2 = (u16*)(ws + 0);          // 1,572,864
  u16*   w2t2 = (u16*)(ws + 1572864);    // 1,572,864
  u16*   rwh  = (u16*)(ws + 3145728);    // 131,072
  u16*   rwl  = (u16*)(ws + 3276800);    // 131,072
  float* regb = (float*)(ws + 3407872);  // 8,192
  u16*   xh   = (u16*)(ws + 3416064);    // 16,777,216
  u16*   xl   = (u16*)(ws + 20193280);   // 16,777,216 (dead after k_router)
  float* part = (float*)(ws + 20193280); // 98,304 — overlays xl, written after router
  float* hid  = (float*)(ws + 36970496); // 33,554,432
  float* selw = (float*)(ws + 70524928); // 786,432

  k_transpose<<<384,256,0,stream>>>(w1, w2, w1t2, w2t2);
  k_prep_rw1<<<264,256,0,stream>>>(rw1, rb1, regime, rwh, rwl, regb);
  k_ln<<<8192,256,0,stream>>>(x, ln_g, ln_b, xh, xl);
  k_router<<<512,256,0,stream>>>(xh, xl, rwh, rwl, regb, hid);
  k_logits<<<2048,256,0,stream>>>(hid, rw2, rb2, selw, part);
  k_aux<<<1,256,0,stream>>>(part, outp);
  k_experts<<<256,512,0,stream>>>(xh, w1t2, w2t2, b1, b2, selw, x, outp);
}

// Round 11
// 238.323 us; speedup vs baseline: 1.9472x; 1.4131x over previous
//
#include <hip/hip_runtime.h>
#include <cmath>

typedef unsigned short u16;
typedef __attribute__((ext_vector_type(8))) short bf16x8;
typedef __attribute__((ext_vector_type(4))) float f32x4;
typedef __attribute__((ext_vector_type(16))) float f32x16;

#define MFMA(a,b,c)   __builtin_amdgcn_mfma_f32_16x16x32_bf16((a),(b),(c),0,0,0)
#define MFMA32(a,b,c) __builtin_amdgcn_mfma_f32_32x32x16_bf16((a),(b),(c),0,0,0)

__device__ __forceinline__ float bf2f(u16 u){ return __uint_as_float(((unsigned)u)<<16); }
__device__ __forceinline__ u16 f2bf(float f){
  unsigned x = __float_as_uint(f);
  return (u16)((x + 0x7FFFu + ((x>>16)&1u)) >> 16);
}

__device__ __forceinline__ void gll16(const u16* g, u16* l){
  __builtin_amdgcn_global_load_lds((const __attribute__((address_space(1))) unsigned*)g,
                                   (__attribute__((address_space(3))) unsigned*)l, 16, 0, 0);
}

// ---------- prep: transpose + re-layout to slab-contiguous bf16 ----------
// w1 (E,D,H) -> w1t2[e][kd=d>>4][h][d&15]  (slab (e,kd) = 512 rows x 32B = 16KB)
// w2 (E,H,D) -> w2t2[e][kh=h>>4][d][h&15]  (slab (e,kh) = 256 rows x 32B = 8KB)
__global__ __launch_bounds__(256) void k_transpose(const float* __restrict__ w1,
        const float* __restrict__ w2, u16* __restrict__ w1t2, u16* __restrict__ w2t2){
  __shared__ u16 t[64][66];
  int b = blockIdx.x;
  int c0 = threadIdx.x & 63, r0 = threadIdx.x >> 6;
  if (b < 192){            // w1: src (D=256 x H=512)
    int e = b >> 5, tl = b & 31;
    int tr = (tl >> 3) << 6, tc = (tl & 7) << 6;
    const float* src = w1 + (size_t)e*131072;
    u16* dst = w1t2 + (size_t)e*131072;
    #pragma unroll
    for (int i=0;i<16;++i){
      int r = r0 + i*4;
      t[c0][r] = f2bf(src[(size_t)(tr+r)*512 + tc + c0]);   // coalesced along H
    }
    __syncthreads();
    #pragma unroll
    for (int i=0;i<16;++i){
      int cc = r0 + i*4;
      int h = tc + cc, d = tr + c0;
      dst[(size_t)((d>>4)*512 + h)*16 + (d&15)] = t[cc][c0];
    }
  } else {                 // w2: src (H=512 x D=256)
    int bb = b - 192;
    int e = bb >> 5, tl = bb & 31;
    int tr = (tl >> 2) << 6, tc = (tl & 3) << 6;
    const float* src = w2 + (size_t)e*131072;
    u16* dst = w2t2 + (size_t)e*131072;
    #pragma unroll
    for (int i=0;i<16;++i){
      int r = r0 + i*4;
      t[c0][r] = f2bf(src[(size_t)(tr+r)*256 + tc + c0]);   // coalesced along D
    }
    __syncthreads();
    #pragma unroll
    for (int i=0;i<16;++i){
      int cc = r0 + i*4;
      int d = tc + cc, h = tr + c0;
      dst[(size_t)((h>>4)*256 + d)*16 + (h&15)] = t[cc][c0];
    }
  }
}

// rw1 (261,256): first 256 rows -> [j][d] hi/lo bf16; rows 256..260 + rb1 folded into regb[b][j].
__global__ void k_prep_rw1(const float* __restrict__ rw1, const float* __restrict__ rb1,
                           const float* __restrict__ regime,
                           u16* __restrict__ rwh, u16* __restrict__ rwl,
                           float* __restrict__ regb){
  int idx = blockIdx.x*256 + threadIdx.x;  // 65536 + 2048 total
  if (idx < 65536){
    int dd = idx & 255, j = idx >> 8;
    float w = rw1[dd*256 + j];
    u16 hi = f2bf(w);
    rwh[idx] = hi;
    rwl[idx] = f2bf(w - bf2f(hi));
  } else {
    int i = idx - 65536; int j = i & 255, b = i >> 8;
    float v = rb1[j];
    #pragma unroll
    for (int r=0;r<5;++r) v += regime[b*5+r]*rw1[(256+r)*256 + j];
    regb[b*256 + j] = v;
  }
}

// ---------- LayerNorm: x -> xn hi/lo bf16 (wave per token) ----------
__global__ __launch_bounds__(256) void k_ln(const float* __restrict__ x,
        const float* __restrict__ g, const float* __restrict__ bta,
        u16* __restrict__ xh, u16* __restrict__ xl){
  int wv = threadIdx.x >> 6, lane = threadIdx.x & 63;
  int t = blockIdx.x*4 + wv;
  float4 v = ((const float4*)(x + (size_t)t*256))[lane];
  float s  = v.x+v.y+v.z+v.w;
  float ss = v.x*v.x+v.y*v.y+v.z*v.z+v.w*v.w;
  #pragma unroll
  for (int m=32;m>=1;m>>=1){ s += __shfl_xor(s,m); ss += __shfl_xor(ss,m); }
  float mu  = s*(1.f/256.f);
  float var = ss*(1.f/256.f) - mu*mu;
  float inv = 1.f / sqrtf(var + 1e-5f);
  float4 gv = ((const float4*)g)[lane];
  float4 bv = ((const float4*)bta)[lane];
  float xv[4] = {v.x,v.y,v.z,v.w};
  float gg[4] = {gv.x,gv.y,gv.z,gv.w};
  float bb[4] = {bv.x,bv.y,bv.z,bv.w};
  u16 hh[4], ll[4];
  #pragma unroll
  for (int q=0;q<4;++q){
    float xn = (xv[q]-mu)*inv*gg[q] + bb[q];
    u16 h = f2bf(xn);
    hh[q] = h;
    ll[q] = f2bf(xn - bf2f(h));
  }
  ((ushort4*)(xh + (size_t)t*256))[lane] = make_ushort4(hh[0],hh[1],hh[2],hh[3]);
  ((ushort4*)(xl + (size_t)t*256))[lane] = make_ushort4(ll[0],ll[1],ll[2],ll[3]);
}

// ---------- router GEMM (hi/lo MFMA, weight frags direct from L2) ----------
__global__ __launch_bounds__(256,2) void k_router(const u16* __restrict__ xh, const u16* __restrict__ xl,
        const u16* __restrict__ rwh, const u16* __restrict__ rwl,
        const float* __restrict__ regb, float* __restrict__ hid){
  __shared__ u16 ash[64*264];
  __shared__ u16 asl[64*264];
  int tid = threadIdx.x;
  int lane = tid & 63, wv = tid >> 6;
  int lr = lane & 15, lg = lane >> 4;
  int tb = blockIdx.x * 64;
  for (int c = tid; c < 2048; c += 256){
    int r = c >> 5, cc = c & 31;
    *(uint4*)(&ash[r*264 + cc*8]) = *(const uint4*)(xh + (size_t)(tb+r)*256 + cc*8);
    *(uint4*)(&asl[r*264 + cc*8]) = *(const uint4*)(xl + (size_t)(tb+r)*256 + cc*8);
  }
  __syncthreads();
  f32x4 acc[4][4];
  #pragma unroll
  for (int mf=0;mf<4;++mf)
    #pragma unroll
    for (int nf=0;nf<4;++nf) acc[mf][nf] = (f32x4){0.f,0.f,0.f,0.f};

  const u16* bhb = rwh + (size_t)wv*64*256;
  const u16* blb = rwl + (size_t)wv*64*256;
  #pragma unroll
  for (int kt=0;kt<8;++kt){
    bf16x8 ah[4], al[4], bh[4], bl[4];
    #pragma unroll
    for (int nf=0;nf<4;++nf){
      bh[nf] = *(const bf16x8*)(bhb + (size_t)(nf*16+lr)*256 + kt*32 + lg*8);
      bl[nf] = *(const bf16x8*)(blb + (size_t)(nf*16+lr)*256 + kt*32 + lg*8);
    }
    #pragma unroll
    for (int mf=0;mf<4;++mf){
      ah[mf] = *(const bf16x8*)(&ash[(mf*16+lr)*264 + kt*32 + lg*8]);
      al[mf] = *(const bf16x8*)(&asl[(mf*16+lr)*264 + kt*32 + lg*8]);
    }
    #pragma unroll
    for (int mf=0;mf<4;++mf)
      #pragma unroll
      for (int nf=0;nf<4;++nf){
        acc[mf][nf] = MFMA(ah[mf], bh[nf], acc[mf][nf]);
        acc[mf][nf] = MFMA(al[mf], bh[nf], acc[mf][nf]);
        acc[mf][nf] = MFMA(ah[mf], bl[nf], acc[mf][nf]);
      }
  }
  int b = tb >> 12;
  #pragma unroll
  for (int mf=0;mf<4;++mf)
    #pragma unroll
    for (int nf=0;nf<4;++nf){
      int j = wv*64 + nf*16 + lr;
      float rbv = regb[b*256 + j];
      #pragma unroll
      for (int r=0;r<4;++r){
        int t = tb + mf*16 + lg*4 + r;
        float v = acc[mf][nf][r] + rbv;
        hid[(size_t)t*256 + j] = v/(1.f+__expf(-v));
      }
    }
}

// ---------- logits + top2 + gates + aux partials ----------
__global__ __launch_bounds__(256) void k_logits(const float* __restrict__ hid,
        const float* __restrict__ rw2, const float* __restrict__ rb2,
        float* __restrict__ selw, float* __restrict__ partials){
  __shared__ float psum[6], pcnt[6];
  int tid = threadIdx.x;
  if (tid < 6){ psum[tid]=0.f; pcnt[tid]=0.f; }
  __syncthreads();
  int lane = tid & 63;
  int lr = lane & 15, lg = lane >> 4;
  int t = blockIdx.x*16 + (tid>>6)*4 + lg;
  float lacc[6] = {0.f,0.f,0.f,0.f,0.f,0.f};
  const float4* hp = (const float4*)(hid + (size_t)t*256);
  #pragma unroll
  for (int p=0;p<4;++p){
    float4 h4 = hp[p*16 + lr];
    float hv[4] = {h4.x,h4.y,h4.z,h4.w};
    int j0 = (p*16+lr)*4;
    #pragma unroll
    for (int q=0;q<4;++q)
      #pragma unroll
      for (int e=0;e<6;++e) lacc[e] += hv[q]*rw2[(j0+q)*6+e];
  }
  #pragma unroll
  for (int m=1;m<16;m<<=1)
    #pragma unroll
    for (int e=0;e<6;++e) lacc[e] += __shfl_xor(lacc[e], m);
  if (lr == 0){
    float lgv[6];
    #pragma unroll
    for (int e=0;e<6;++e) lgv[e] = lacc[e] + rb2[e];
    int i0=0; float v0=lgv[0];
    #pragma unroll
    for (int e=1;e<6;++e) if (lgv[e] > v0){ v0=lgv[e]; i0=e; }
    int i1=-1; float v1=-1e30f;
    #pragma unroll
    for (int e=0;e<6;++e) if (e!=i0 && lgv[e] > v1){ v1=lgv[e]; i1=e; }
    float ex = expf(v1-v0);
    float w0 = 1.f/(1.f+ex), w1 = ex/(1.f+ex);
    #pragma unroll
    for (int e=0;e<6;++e) selw[(size_t)t*6+e] = (e==i0)? w0 : (e==i1)? w1 : 0.f;
    float ps=0.f, p[6];
    #pragma unroll
    for (int e=0;e<6;++e){ p[e]=expf(lgv[e]-v0); ps+=p[e]; }
    float rinv = 1.f/ps;
    #pragma unroll
    for (int e=0;e<6;++e) atomicAdd(&psum[e], p[e]*rinv);
    atomicAdd(&pcnt[i0], 1.f);
  }
  __syncthreads();
  if (tid < 6){
    partials[blockIdx.x*12 + tid] = psum[tid];
    partials[blockIdx.x*12 + 6 + tid] = pcnt[tid];
  }
}

__global__ __launch_bounds__(256) void k_aux(const float* __restrict__ partials, float* __restrict__ outp){
  __shared__ float a[12];
  int tid = threadIdx.x;
  if (tid < 12) a[tid] = 0.f;
  __syncthreads();
  int col = tid & 15, seg = tid >> 4;
  if (col < 12){
    float s = 0.f;
    for (int i=seg; i<2048; i+=16) s += partials[i*12+col];
    atomicAdd(&a[col], s);
  }
  __syncthreads();
  if (tid==0){
    float aux=0.f;
    #pragma unroll
    for (int e=0;e<6;++e) aux += a[e]*a[6+e];
    aux *= 0.01f*6.f/(32768.f*32768.f);
    outp[8388608] = aux;
  }
}

// ---------- fused all-expert MLP v7: gate folded into hs, no oacc, depth-4 prefetch ----------
// 64-token tiles, 512 blocks, 8 waves. Slot-major LDS (conflict-free):
//   xs [s=0..31][tok=0..63] 16B cells -> u16 idx = s*512 + tok*8              (32 KB)
//   hs [sh=0..31][tok=0..63] at +16384 (stores g[t,e]*silu(...))              (32 KB)
// GEMM2 accumulator a2 IS the output accumulator (gate pre-folded); b2 term
// added post-loop as rank-6 correction. Peak acc live = a1(32)+a2(32) = 64 regs.
__global__ __launch_bounds__(512,2) void k_experts(const u16* __restrict__ xh,
        const u16* __restrict__ w1t2, const u16* __restrict__ w2t2,
        const float* __restrict__ b1g, const float* __restrict__ b2g,
        const float* __restrict__ selw, const float* __restrict__ xg,
        float* __restrict__ outp){
  __shared__ u16 lds[32768];
  __shared__ float wsl[384];
  int tid = threadIdx.x;
  int lane = tid & 63, wv = tid >> 6;
  int l31 = lane & 31, l5 = lane >> 5;
  int tb = blockIdx.x * 64;

  // stage xs: linear LDS dest (slot-major), row-gathered global source
  #pragma unroll
  for (int it=0; it<4; ++it){
    int gcell = it*512 + tid;
    int s = gcell >> 6, row = gcell & 63;
    gll16(xh + (size_t)(tb+row)*256 + s*8, lds + gcell*8);
  }
  if (tid < 384) wsl[tid] = selw[(size_t)tb*6 + tid];
  __syncthreads();

  f32x16 a2t0 = (f32x16)(0.f), a2t1 = (f32x16)(0.f);   // output accumulator (gate folded)

  for (int e=0;e<6;++e){
    #pragma unroll
    for (int hh=0;hh<2;++hh){
      // ---- GEMM1: wave owns 32 h-rows (hh*256 + wv*32), K=256, depth-4 prefetch ----
      f32x16 a1t0 = (f32x16)(0.f), a1t1 = (f32x16)(0.f);
      const u16* w1b = w1t2 + (size_t)e*131072 + (size_t)(hh*256 + wv*32)*16 + l31*16 + l5*8;
      {
        bf16x8 p0 = *(const bf16x8*)(w1b);
        bf16x8 p1 = *(const bf16x8*)(w1b + 8192);
        bf16x8 p2 = *(const bf16x8*)(w1b + 16384);
        bf16x8 p3 = *(const bf16x8*)(w1b + 24576);
        #pragma unroll
        for (int ks=0; ks<16; ++ks){
          bf16x8 cur = p0; p0 = p1; p1 = p2; p2 = p3;
          if (ks+4 < 16) p3 = *(const bf16x8*)(w1b + (ks+4)*8192);
          bf16x8 bx0 = *(const bf16x8*)&lds[(ks*2+l5)*512 + l31*8];
          bf16x8 bx1 = *(const bf16x8*)&lds[(ks*2+l5)*512 + (l31+32)*8];
          a1t0 = MFMA32(cur, bx0, a1t0);
          a1t1 = MFMA32(cur, bx1, a1t1);
        }
      }
      __syncthreads();   // previous hs readers done
      // ---- epilogue: bias + silu, SCALED BY GATE, -> hs (slot-major) ----
      {
        float g0 = wsl[l31*6 + e];
        float g1 = wsl[(32+l31)*6 + e];
        #pragma unroll
        for (int rq=0;rq<4;++rq){
          float4 b4 = *(const float4*)(b1g + (size_t)e*512 + hh*256 + wv*32 + rq*8 + l5*4);
          float bb[4] = {b4.x,b4.y,b4.z,b4.w};
          float sv0[4], sv1[4];
          #pragma unroll
          for (int q=0;q<4;++q){
            float v0 = a1t0[rq*4+q] + bb[q];
            float v1 = a1t1[rq*4+q] + bb[q];
            sv0[q] = g0 * (v0/(1.f+__expf(-v0)));
            sv1[q] = g1 * (v1/(1.f+__expf(-v1)));
          }
          unsigned p00 = (unsigned)f2bf(sv0[0]) | ((unsigned)f2bf(sv0[1])<<16);
          unsigned p01 = (unsigned)f2bf(sv0[2]) | ((unsigned)f2bf(sv0[3])<<16);
          unsigned p10 = (unsigned)f2bf(sv1[0]) | ((unsigned)f2bf(sv1[1])<<16);
          unsigned p11 = (unsigned)f2bf(sv1[2]) | ((unsigned)f2bf(sv1[3])<<16);
          int sbase = 16384 + (wv*4+rq)*512 + l5*4;
          *(uint2*)&lds[sbase + l31*8]      = make_uint2(p00,p01);
          *(uint2*)&lds[sbase + (l31+32)*8] = make_uint2(p10,p11);
        }
      }
      __syncthreads();   // hs ready
      // ---- GEMM2: wave owns 32 d-rows, K = this h-half (256), accumulate into a2 ----
      const u16* w2b = w2t2 + (size_t)e*131072 + (size_t)(hh*16)*4096 + (size_t)(wv*32 + l31)*16 + l5*8;
      {
        bf16x8 p0 = *(const bf16x8*)(w2b);
        bf16x8 p1 = *(const bf16x8*)(w2b + 4096);
        bf16x8 p2 = *(const bf16x8*)(w2b + 8192);
        bf16x8 p3 = *(const bf16x8*)(w2b + 12288);
        #pragma unroll
        for (int ks=0; ks<16; ++ks){
          bf16x8 cur = p0; p0 = p1; p1 = p2; p2 = p3;
          if (ks+4 < 16) p3 = *(const bf16x8*)(w2b + (ks+4)*4096);
          bf16x8 h0 = *(const bf16x8*)&lds[16384 + (ks*2+l5)*512 + l31*8];
          bf16x8 h1 = *(const bf16x8*)&lds[16384 + (ks*2+l5)*512 + (l31+32)*8];
          a2t0 = MFMA32(cur, h0, a2t0);
          a2t1 = MFMA32(cur, h1, a2t1);
        }
      }
    }
  }
  // ---- rank-6 b2 correction: out += sum_e g[t,e] * b2[e,d] ----
  #pragma unroll
  for (int e=0;e<6;++e){
    float g0 = wsl[l31*6 + e];
    float g1 = wsl[(32+l31)*6 + e];
    #pragma unroll
    for (int rq=0;rq<4;++rq){
      float4 b4 = *(const float4*)(b2g + (size_t)e*256 + wv*32 + rq*8 + l5*4);
      a2t0[rq*4+0] += g0*b4.x; a2t0[rq*4+1] += g0*b4.y;
      a2t0[rq*4+2] += g0*b4.z; a2t0[rq*4+3] += g0*b4.w;
      a2t1[rq*4+0] += g1*b4.x; a2t1[rq*4+1] += g1*b4.y;
      a2t1[rq*4+2] += g1*b4.z; a2t1[rq*4+3] += g1*b4.w;
    }
  }
  // ---- residual + store ----
  #pragma unroll
  for (int rq=0;rq<4;++rq){
    int d = wv*32 + rq*8 + l5*4;
    int t0 = tb + l31, t1 = tb + 32 + l31;
    float4 x0 = *(const float4*)(xg + (size_t)t0*256 + d);
    float4 x1 = *(const float4*)(xg + (size_t)t1*256 + d);
    float4 o0, o1;
    o0.x = x0.x + a2t0[rq*4+0]; o0.y = x0.y + a2t0[rq*4+1];
    o0.z = x0.z + a2t0[rq*4+2]; o0.w = x0.w + a2t0[rq*4+3];
    o1.x = x1.x + a2t1[rq*4+0]; o1.y = x1.y + a2t1[rq*4+1];
    o1.z = x1.z + a2t1[rq*4+2]; o1.w = x1.w + a2t1[rq*4+3];
    *(float4*)(outp + (size_t)t0*256 + d) = o0;
    *(float4*)(outp + (size_t)t1*256 + d) = o1;
  }
}

extern "C" void kernel_launch(void* const* d_in, const int* in_sizes, int n_in,
                              void* d_out, int out_size, void* d_ws, size_t ws_size,
                              hipStream_t stream){
  const float* x      = (const float*)d_in[0];
  const float* regime = (const float*)d_in[1];
  const float* ln_g   = (const float*)d_in[2];
  const float* ln_b   = (const float*)d_in[3];
  const float* w1     = (const float*)d_in[4];
  const float* b1     = (const float*)d_in[5];
  const float* w2     = (const float*)d_in[6];
  const float* b2     = (const float*)d_in[7];
  const float* rw1    = (const float*)d_in[8];
  const float* rb1    = (const float*)d_in[9];
  const float* rw2    = (const float*)d_in[10];
  const float* rb2    = (const float*)d_in[11];
  float* outp = (float*)d_out;
  char* ws = (char*)d_ws;

  u16*   w1t2 = (u16*)(ws + 0);          // 1,572,864
  u16*   w2t2 = (u16*)(ws + 1572864);    // 1,572,864
  u16*   rwh  = (u16*)(ws + 3145728);    // 131,072
  u16*   rwl  = (u16*)(ws + 3276800);    // 131,072
  float* regb = (float*)(ws + 3407872);  // 8,192
  u16*   xh   = (u16*)(ws + 3416064);    // 16,777,216
  u16*   xl   = (u16*)(ws + 20193280);   // 16,777,216 (dead after k_router)
  float* part = (float*)(ws + 20193280); // 98,304 — overlays xl, written after router
  float* hid  = (float*)(ws + 36970496); // 33,554,432
  float* selw = (float*)(ws + 70524928); // 786,432

  k_transpose<<<384,256,0,stream>>>(w1, w2, w1t2, w2t2);
  k_prep_rw1<<<264,256,0,stream>>>(rw1, rb1, regime, rwh, rwl, regb);
  k_ln<<<8192,256,0,stream>>>(x, ln_g, ln_b, xh, xl);
  k_router<<<512,256,0,stream>>>(xh, xl, rwh, rwl, regb, hid);
  k_logits<<<2048,256,0,stream>>>(hid, rw2, rb2, selw, part);
  k_aux<<<1,256,0,stream>>>(part, outp);
  k_experts<<<512,512,0,stream>>>(xh, w1t2, w2t2, b1, b2, selw, x, outp);
}